// Round 1
// baseline (880.208 us; speedup 1.0000x reference)
//
#include <hip/hip_runtime.h>
#include <hip/hip_bf16.h>

#define S_LEN 4096
#define DMODEL 2048
#define NHEADS 16
#define HEADDIM 128

typedef __attribute__((ext_vector_type(8))) short bf16x8;
typedef __attribute__((ext_vector_type(4))) float f32x4;

__device__ __forceinline__ float bf2f(ushort u) {
  union { unsigned int i; float f; } x; x.i = ((unsigned int)u) << 16; return x.f;
}
__device__ __forceinline__ ushort f2bf(float f) {
  union { float f; unsigned int i; } x; x.f = f;
  unsigned int u = x.i;
  unsigned int r = u + 0x7fffu + ((u >> 16) & 1u);
  return (ushort)(r >> 16);
}

// ---------------- RoPE cos/sin table: [S][64] each ----------------
__global__ __launch_bounds__(256) void rope_table_kernel(float* __restrict__ cosT,
                                                         float* __restrict__ sinT) {
  int idx = blockIdx.x * 256 + threadIdx.x;  // S*64
  int t = idx >> 6, j = idx & 63;
  float expo = (float)(2 * j) / 128.0f;
  float inv = 1.0f / powf(10000.0f, expo);
  float f = (float)t * inv;
  cosT[idx] = cosf(f);
  sinT[idx] = sinf(f);
}

// ---------------- split-bf16 GEMM: C = A * B^T ----------------
// A: [M,K] f32, B: [N,K] f32 (row-major, contract over K = contiguous dim of both)
// C = Ah*Bh + Ah*Bl + Al*Bh accumulated fp32 via MFMA -> ~fp32 accuracy
#define BM 128
#define BN 128
#define BK 32
#define LDT 40  // BK + 8 pad (ushorts): row stride 80B, 16B-aligned, 2-way banks

__global__ __launch_bounds__(256) void gemm_bt_split(const float* __restrict__ A,
                                                     const float* __restrict__ B,
                                                     void* __restrict__ Cout,
                                                     int M, int N, int K, int f32out) {
  __shared__ ushort Ah[BM * LDT], Al[BM * LDT], Bh[BM * LDT], Bl[BM * LDT];
  const int tid = threadIdx.x;
  const int wave = tid >> 6, lane = tid & 63;
  const int lg = lane >> 4, lm = lane & 15;
  const int m0 = blockIdx.y * BM, n0 = blockIdx.x * BN;
  const int wm = (wave >> 1) * 64, wn = (wave & 1) * 64;
  f32x4 acc[4][4] = {};

  for (int k0 = 0; k0 < K; k0 += BK) {
    __syncthreads();
#pragma unroll
    for (int it = 0; it < 4; ++it) {
      int i = tid + it * 256;        // 1024 float4-chunks: 128 rows x 8
      int r = i >> 3, c = (i & 7) << 2;
      float4 a = *reinterpret_cast<const float4*>(&A[(size_t)(m0 + r) * K + k0 + c]);
      float4 b = *reinterpret_cast<const float4*>(&B[(size_t)(n0 + r) * K + k0 + c]);
      unsigned int ua0 = __float_as_uint(a.x), ua1 = __float_as_uint(a.y);
      unsigned int ua2 = __float_as_uint(a.z), ua3 = __float_as_uint(a.w);
      ushort4 hi, lo;
      hi.x = (ushort)(ua0 >> 16); lo.x = f2bf(a.x - __uint_as_float(ua0 & 0xffff0000u));
      hi.y = (ushort)(ua1 >> 16); lo.y = f2bf(a.y - __uint_as_float(ua1 & 0xffff0000u));
      hi.z = (ushort)(ua2 >> 16); lo.z = f2bf(a.z - __uint_as_float(ua2 & 0xffff0000u));
      hi.w = (ushort)(ua3 >> 16); lo.w = f2bf(a.w - __uint_as_float(ua3 & 0xffff0000u));
      *reinterpret_cast<ushort4*>(&Ah[r * LDT + c]) = hi;
      *reinterpret_cast<ushort4*>(&Al[r * LDT + c]) = lo;
      unsigned int ub0 = __float_as_uint(b.x), ub1 = __float_as_uint(b.y);
      unsigned int ub2 = __float_as_uint(b.z), ub3 = __float_as_uint(b.w);
      hi.x = (ushort)(ub0 >> 16); lo.x = f2bf(b.x - __uint_as_float(ub0 & 0xffff0000u));
      hi.y = (ushort)(ub1 >> 16); lo.y = f2bf(b.y - __uint_as_float(ub1 & 0xffff0000u));
      hi.z = (ushort)(ub2 >> 16); lo.z = f2bf(b.z - __uint_as_float(ub2 & 0xffff0000u));
      hi.w = (ushort)(ub3 >> 16); lo.w = f2bf(b.w - __uint_as_float(ub3 & 0xffff0000u));
      *reinterpret_cast<ushort4*>(&Bh[r * LDT + c]) = hi;
      *reinterpret_cast<ushort4*>(&Bl[r * LDT + c]) = lo;
    }
    __syncthreads();
    bf16x8 ah[4], al[4], bh[4], bl[4];
#pragma unroll
    for (int t = 0; t < 4; ++t) {
      ah[t] = *reinterpret_cast<const bf16x8*>(&Ah[(wm + t * 16 + lm) * LDT + lg * 8]);
      al[t] = *reinterpret_cast<const bf16x8*>(&Al[(wm + t * 16 + lm) * LDT + lg * 8]);
      bh[t] = *reinterpret_cast<const bf16x8*>(&Bh[(wn + t * 16 + lm) * LDT + lg * 8]);
      bl[t] = *reinterpret_cast<const bf16x8*>(&Bl[(wn + t * 16 + lm) * LDT + lg * 8]);
    }
#pragma unroll
    for (int mi = 0; mi < 4; ++mi)
#pragma unroll
      for (int ni = 0; ni < 4; ++ni) {
        acc[mi][ni] = __builtin_amdgcn_mfma_f32_16x16x32_bf16(ah[mi], bh[ni], acc[mi][ni], 0, 0, 0);
        acc[mi][ni] = __builtin_amdgcn_mfma_f32_16x16x32_bf16(ah[mi], bl[ni], acc[mi][ni], 0, 0, 0);
        acc[mi][ni] = __builtin_amdgcn_mfma_f32_16x16x32_bf16(al[mi], bh[ni], acc[mi][ni], 0, 0, 0);
      }
  }
  // epilogue: C/D layout col = lane&15, row = (lane>>4)*4 + j
  if (f32out) {
    float* C = (float*)Cout;
#pragma unroll
    for (int mi = 0; mi < 4; ++mi)
#pragma unroll
      for (int ni = 0; ni < 4; ++ni)
#pragma unroll
        for (int j = 0; j < 4; ++j) {
          int row = m0 + wm + mi * 16 + lg * 4 + j;
          int col = n0 + wn + ni * 16 + lm;
          C[(size_t)row * N + col] = acc[mi][ni][j];
        }
  } else {
    ushort* C = (ushort*)Cout;
#pragma unroll
    for (int mi = 0; mi < 4; ++mi)
#pragma unroll
      for (int ni = 0; ni < 4; ++ni)
#pragma unroll
        for (int j = 0; j < 4; ++j) {
          int row = m0 + wm + mi * 16 + lg * 4 + j;
          int col = n0 + wn + ni * 16 + lm;
          C[(size_t)row * N + col] = f2bf(acc[mi][ni][j]);
        }
  }
}

// ---------------- RoPE apply: Qr/Kr (bf16) -> Q hi/lo (scaled by 1/sqrt(HD)), K bf16 ----------------
__global__ __launch_bounds__(256) void rope_kernel(const ushort* __restrict__ Qr,
                                                   const ushort* __restrict__ Kr,
                                                   const int* __restrict__ pos,
                                                   const float* __restrict__ cosT,
                                                   const float* __restrict__ sinT,
                                                   ushort* __restrict__ Qbh,
                                                   ushort* __restrict__ Qbl,
                                                   ushort* __restrict__ Kb) {
  int idx = blockIdx.x * 256 + threadIdx.x;  // S*D
  int s = idx >> 11, d = idx & 2047;
  int r = d & 127, j = r & 63;
  int p = pos[s];
  float cs = cosT[p * 64 + j], sn = sinT[p * 64 + j];
  float q1 = bf2f(Qr[idx]), k1 = bf2f(Kr[idx]);
  int other = (r < 64) ? idx + 64 : idx - 64;
  float q2 = bf2f(Qr[other]), k2 = bf2f(Kr[other]);
  float sgn = (r < 64) ? -1.0f : 1.0f;
  float qo = (q1 * cs + sgn * q2 * sn) * 0.08838834764831845f;  // 1/sqrt(128)
  float ko = k1 * cs + sgn * k2 * sn;
  unsigned int uq = __float_as_uint(qo);
  Qbh[idx] = (ushort)(uq >> 16);
  Qbl[idx] = f2bf(qo - __uint_as_float(uq & 0xffff0000u));
  Kb[idx] = f2bf(ko);
}

// ---------------- V transpose: Vr [S][D] -> Vt [D][S] (bf16) ----------------
__global__ __launch_bounds__(256) void transpose_kernel(const ushort* __restrict__ Vr,
                                                        ushort* __restrict__ Vt) {
  __shared__ ushort tile[64 * 72];
  int tid = threadIdx.x;
  int s0 = blockIdx.x * 64, c0 = blockIdx.y * 64;
#pragma unroll
  for (int it = 0; it < 2; ++it) {
    int i = tid + it * 256;  // 512 chunks of 8
    int r = i >> 3, c = i & 7;
    *reinterpret_cast<uint4*>(&tile[r * 72 + c * 8]) =
        *reinterpret_cast<const uint4*>(&Vr[(size_t)(s0 + r) * DMODEL + c0 + c * 8]);
  }
  __syncthreads();
#pragma unroll
  for (int it = 0; it < 2; ++it) {
    int i = tid + it * 256;
    int cr = i >> 3, sc = i & 7;
    ushort tmp[8];
#pragma unroll
    for (int j = 0; j < 8; ++j) tmp[j] = tile[(sc * 8 + j) * 72 + cr];
    *reinterpret_cast<uint4*>(&Vt[(size_t)(c0 + cr) * S_LEN + s0 + sc * 8]) =
        *reinterpret_cast<uint4*>(tmp);
  }
}

// ---------------- Flash attention ----------------
// grid: (S/QBLK, H). 4 waves, each owns 16 q-rows. Q split hi/lo (2-term QK^T).
#define QBLK 64
#define KBLK 64
#define KLD 136  // 128 + 8 pad (ushorts)
#define VLD 72   // 64 + 8
#define PLD 72

__global__ __launch_bounds__(256) void flash_kernel(const ushort* __restrict__ Qh,
                                                    const ushort* __restrict__ Ql,
                                                    const ushort* __restrict__ Kb,
                                                    const ushort* __restrict__ Vt,
                                                    float* __restrict__ Of) {
  __shared__ ushort Kt[KBLK * KLD];
  __shared__ ushort Vs[HEADDIM * VLD];
  __shared__ ushort Ps[4][16 * PLD];
  const int tid = threadIdx.x;
  const int wave = tid >> 6, lane = tid & 63;
  const int lg = lane >> 4, lm = lane & 15;
  const int h = blockIdx.y;
  const int q0 = blockIdx.x * QBLK;
  const int qrow = q0 + wave * 16 + lm;

  bf16x8 qh[4], ql[4];
#pragma unroll
  for (int kc = 0; kc < 4; ++kc) {
    size_t off = (size_t)qrow * DMODEL + h * HEADDIM + kc * 32 + lg * 8;
    qh[kc] = *reinterpret_cast<const bf16x8*>(&Qh[off]);
    ql[kc] = *reinterpret_cast<const bf16x8*>(&Ql[off]);
  }
  f32x4 oacc[8] = {};
  float mrun[4], lrun[4];
#pragma unroll
  for (int j = 0; j < 4; ++j) { mrun[j] = -3.0e38f; lrun[j] = 0.0f; }

  for (int k0 = 0; k0 < S_LEN; k0 += KBLK) {
    __syncthreads();
#pragma unroll
    for (int it = 0; it < 4; ++it) {
      int i = tid + it * 256;
      int r = i >> 4, c = i & 15;  // K tile: 64 rows x 16 chunks
      *reinterpret_cast<uint4*>(&Kt[r * KLD + c * 8]) =
          *reinterpret_cast<const uint4*>(&Kb[(size_t)(k0 + r) * DMODEL + h * HEADDIM + c * 8]);
      int d = i >> 3, c2 = i & 7;  // V tile: 128 d-rows x 8 chunks
      *reinterpret_cast<uint4*>(&Vs[d * VLD + c2 * 8]) =
          *reinterpret_cast<const uint4*>(&Vt[(size_t)(h * HEADDIM + d) * S_LEN + k0 + c2 * 8]);
    }
    __syncthreads();

    // QK^T: S[16 q x 64 keys], 2-term (Q hi + Q lo)
    f32x4 sc4[4] = {};
#pragma unroll
    for (int nf = 0; nf < 4; ++nf) {
#pragma unroll
      for (int kc = 0; kc < 4; ++kc) {
        bf16x8 kfrag = *reinterpret_cast<const bf16x8*>(&Kt[(nf * 16 + lm) * KLD + kc * 32 + lg * 8]);
        sc4[nf] = __builtin_amdgcn_mfma_f32_16x16x32_bf16(qh[kc], kfrag, sc4[nf], 0, 0, 0);
        sc4[nf] = __builtin_amdgcn_mfma_f32_16x16x32_bf16(ql[kc], kfrag, sc4[nf], 0, 0, 0);
      }
    }

    // online softmax (rows owned by wave; reduce across 16 lanes of group)
    float mt[4];
#pragma unroll
    for (int j = 0; j < 4; ++j)
      mt[j] = fmaxf(fmaxf(sc4[0][j], sc4[1][j]), fmaxf(sc4[2][j], sc4[3][j]));
#pragma unroll
    for (int off = 1; off < 16; off <<= 1)
#pragma unroll
      for (int j = 0; j < 4; ++j) mt[j] = fmaxf(mt[j], __shfl_xor(mt[j], off));

    float scl[4], rs[4], pm[4][4];
#pragma unroll
    for (int j = 0; j < 4; ++j) {
      float mn = fmaxf(mrun[j], mt[j]);
      scl[j] = __expf(mrun[j] - mn);
      mrun[j] = mn;
      rs[j] = 0.0f;
    }
#pragma unroll
    for (int nf = 0; nf < 4; ++nf)
#pragma unroll
      for (int j = 0; j < 4; ++j) {
        float p = __expf(sc4[nf][j] - mrun[j]);
        pm[nf][j] = p;
        rs[j] += p;
      }
#pragma unroll
    for (int off = 1; off < 16; off <<= 1)
#pragma unroll
      for (int j = 0; j < 4; ++j) rs[j] += __shfl_xor(rs[j], off);
#pragma unroll
    for (int j = 0; j < 4; ++j) lrun[j] = lrun[j] * scl[j] + rs[j];
#pragma unroll
    for (int nb = 0; nb < 8; ++nb)
#pragma unroll
      for (int j = 0; j < 4; ++j) oacc[nb][j] *= scl[j];

    // P (C-layout) -> LDS -> A-layout fragments
#pragma unroll
    for (int nf = 0; nf < 4; ++nf)
#pragma unroll
      for (int j = 0; j < 4; ++j)
        Ps[wave][(lg * 4 + j) * PLD + nf * 16 + lm] = f2bf(pm[nf][j]);
    bf16x8 pa[2];
#pragma unroll
    for (int kk = 0; kk < 2; ++kk)
      pa[kk] = *reinterpret_cast<const bf16x8*>(&Ps[wave][lm * PLD + kk * 32 + lg * 8]);
#pragma unroll
    for (int nb = 0; nb < 8; ++nb)
#pragma unroll
      for (int kk = 0; kk < 2; ++kk) {
        bf16x8 vfrag = *reinterpret_cast<const bf16x8*>(&Vs[(nb * 16 + lm) * VLD + kk * 32 + lg * 8]);
        oacc[nb] = __builtin_amdgcn_mfma_f32_16x16x32_bf16(pa[kk], vfrag, oacc[nb], 0, 0, 0);
      }
  }

#pragma unroll
  for (int nb = 0; nb < 8; ++nb)
#pragma unroll
    for (int j = 0; j < 4; ++j) {
      int row = q0 + wave * 16 + lg * 4 + j;
      int col = h * HEADDIM + nb * 16 + lm;
      Of[(size_t)row * DMODEL + col] = oacc[nb][j] / lrun[j];
    }
}

extern "C" void kernel_launch(void* const* d_in, const int* in_sizes, int n_in,
                              void* d_out, int out_size, void* d_ws, size_t ws_size,
                              hipStream_t stream) {
  (void)in_sizes; (void)n_in; (void)out_size; (void)ws_size;
  const float* X  = (const float*)d_in[0];
  const float* Wq = (const float*)d_in[1];
  const float* Wk = (const float*)d_in[2];
  const float* Wv = (const float*)d_in[3];
  const float* Wo = (const float*)d_in[4];
  const int* pos  = (const int*)d_in[5];
  float* out = (float*)d_out;
  char* w = (char*)d_ws;
  const size_t SD = (size_t)S_LEN * DMODEL;  // 8388608

  ushort* Qr  = (ushort*)(w);
  ushort* Kr  = (ushort*)(w + 2 * SD);
  ushort* Vr  = (ushort*)(w + 4 * SD);
  ushort* Qbh = (ushort*)(w + 6 * SD);
  ushort* Qbl = (ushort*)(w + 8 * SD);
  ushort* Kb  = (ushort*)(w + 10 * SD);
  ushort* Vt  = (ushort*)(w + 12 * SD);
  float*  Of  = (float*)(w + 14 * SD);
  float* cosT = (float*)(w + 18 * SD);
  float* sinT = (float*)(w + 18 * SD + (size_t)S_LEN * 64 * 4);
  // total ws: 18*SD + 2*S*64*4 = 153.1 MB

  dim3 gemmGrid(DMODEL / BN, S_LEN / BM);
  rope_table_kernel<<<S_LEN * 64 / 256, 256, 0, stream>>>(cosT, sinT);
  gemm_bt_split<<<gemmGrid, 256, 0, stream>>>(X, Wq, Qr, S_LEN, DMODEL, DMODEL, 0);
  gemm_bt_split<<<gemmGrid, 256, 0, stream>>>(X, Wk, Kr, S_LEN, DMODEL, DMODEL, 0);
  gemm_bt_split<<<gemmGrid, 256, 0, stream>>>(X, Wv, Vr, S_LEN, DMODEL, DMODEL, 0);
  rope_kernel<<<SD / 256, 256, 0, stream>>>(Qr, Kr, pos, cosT, sinT, Qbh, Qbl, Kb);
  transpose_kernel<<<dim3(S_LEN / 64, DMODEL / 64), 256, 0, stream>>>(Vr, Vt);
  flash_kernel<<<dim3(S_LEN / QBLK, NHEADS), 256, 0, stream>>>(Qbh, Qbl, Kb, Vt, Of);
  gemm_bt_split<<<gemmGrid, 256, 0, stream>>>(Of, Wo, out, S_LEN, DMODEL, DMODEL, 1);
}

// Round 3
// 690.292 us; speedup vs baseline: 1.2751x; 1.2751x over previous
//
#include <hip/hip_runtime.h>
#include <hip/hip_bf16.h>

#define S_LEN 4096
#define DMODEL 2048
#define NHEADS 16
#define HEADDIM 128

typedef __attribute__((ext_vector_type(8))) short bf16x8;
typedef __attribute__((ext_vector_type(4))) float f32x4;

__device__ __forceinline__ float bf2f(ushort u) {
  union { unsigned int i; float f; } x; x.i = ((unsigned int)u) << 16; return x.f;
}
__device__ __forceinline__ ushort f2bf(float f) {
  union { float f; unsigned int i; } x; x.f = f;
  unsigned int u = x.i;
  unsigned int r = u + 0x7fffu + ((u >> 16) & 1u);
  return (ushort)(r >> 16);
}
__device__ __forceinline__ void splitf(float f, ushort& h, ushort& l) {
  unsigned int u = __float_as_uint(f);
  h = (ushort)(u >> 16);
  l = f2bf(f - __uint_as_float(u & 0xffff0000u));
}

__device__ __forceinline__ void gload16(const ushort* g, ushort* l) {
  __builtin_amdgcn_global_load_lds(
      (const __attribute__((address_space(1))) unsigned int*)g,
      (__attribute__((address_space(3))) unsigned int*)l, 16, 0, 0);
}

// ---------------- RoPE cos/sin table: [S][64] each ----------------
__global__ __launch_bounds__(256) void rope_table_kernel(float* __restrict__ cosT,
                                                         float* __restrict__ sinT) {
  int idx = blockIdx.x * 256 + threadIdx.x;  // S*64
  int t = idx >> 6, j = idx & 63;
  float expo = (float)(2 * j) / 128.0f;
  float inv = 1.0f / powf(10000.0f, expo);
  float f = (float)t * inv;
  cosT[idx] = cosf(f);
  sinT[idx] = sinf(f);
}

// ---------------- fp32 -> bf16 hi/lo split ----------------
__global__ __launch_bounds__(256) void split_kernel(const float* __restrict__ in,
                                                    ushort* __restrict__ hi,
                                                    ushort* __restrict__ lo) {
  int i = (blockIdx.x * 256 + threadIdx.x) * 4;
  float4 v = *reinterpret_cast<const float4*>(&in[i]);
  ushort4 h, l;
  splitf(v.x, h.x, l.x);
  splitf(v.y, h.y, l.y);
  splitf(v.z, h.z, l.z);
  splitf(v.w, h.w, l.w);
  *reinterpret_cast<ushort4*>(&hi[i]) = h;
  *reinterpret_cast<ushort4*>(&lo[i]) = l;
}

// ---------------- 3-term bf16 GEMM: C = (Ah+Al) * (Bh+Bl)^T (drop Al*Bl) ----------------
// A: [M,K] bf16 h/l, B: [N,K] bf16 h/l. 128x128 tile, BK=32, global_load_lds staging.
// LDS linear [128][32] per array with 16B-chunk XOR swizzle: chunk c stored at c^((row>>1)&3).
__global__ __launch_bounds__(256) void gemm3(const ushort* __restrict__ Ah_,
                                             const ushort* __restrict__ Al_,
                                             const ushort* __restrict__ Bh_,
                                             const ushort* __restrict__ Bl_,
                                             void* __restrict__ Cout,
                                             int M, int N, int K, int f32out) {
  __shared__ __align__(16) ushort sAh[128 * 32], sAl[128 * 32], sBh[128 * 32], sBl[128 * 32];
  const int tid = threadIdx.x;
  const int wave = tid >> 6, lane = tid & 63;
  const int lg = lane >> 4, lm = lane & 15;
  // XCD-aware swizzle (nwg % 8 == 0)
  const int nwg = gridDim.x * gridDim.y;
  const int id = blockIdx.y * gridDim.x + blockIdx.x;
  const int cpx = nwg >> 3;
  const int swz = (id & 7) * cpx + (id >> 3);
  const int nbx = N >> 7;
  const int m0 = (swz / nbx) * 128, n0 = (swz % nbx) * 128;
  const int wm = (wave >> 1) * 64, wn = (wave & 1) * 64;
  f32x4 acc[4][4] = {};

  for (int k0 = 0; k0 < K; k0 += 32) {
    __syncthreads();
#pragma unroll
    for (int t = 0; t < 2; ++t) {
      int r = wave * 32 + t * 16 + (lane >> 2);
      int ca = (lane & 3) ^ ((r >> 1) & 3);
      size_t ga = (size_t)(m0 + r) * K + k0 + ca * 8;
      size_t gb = (size_t)(n0 + r) * K + k0 + ca * 8;
      int lb = (wave * 32 + t * 16) * 32;  // wave-uniform LDS base (ushorts)
      gload16(&Ah_[ga], &sAh[lb]);
      gload16(&Al_[ga], &sAl[lb]);
      gload16(&Bh_[gb], &sBh[lb]);
      gload16(&Bl_[gb], &sBl[lb]);
    }
    __syncthreads();
    bf16x8 ah[4], al[4], bh[4], bl[4];
#pragma unroll
    for (int t = 0; t < 4; ++t) {
      int Ra = wm + t * 16 + lm;
      int Rb = wn + t * 16 + lm;
      int ca = (lg ^ ((Ra >> 1) & 3)) * 8;
      int cb = (lg ^ ((Rb >> 1) & 3)) * 8;
      ah[t] = *reinterpret_cast<const bf16x8*>(&sAh[Ra * 32 + ca]);
      al[t] = *reinterpret_cast<const bf16x8*>(&sAl[Ra * 32 + ca]);
      bh[t] = *reinterpret_cast<const bf16x8*>(&sBh[Rb * 32 + cb]);
      bl[t] = *reinterpret_cast<const bf16x8*>(&sBl[Rb * 32 + cb]);
    }
#pragma unroll
    for (int mi = 0; mi < 4; ++mi)
#pragma unroll
      for (int ni = 0; ni < 4; ++ni) {
        acc[mi][ni] = __builtin_amdgcn_mfma_f32_16x16x32_bf16(ah[mi], bh[ni], acc[mi][ni], 0, 0, 0);
        acc[mi][ni] = __builtin_amdgcn_mfma_f32_16x16x32_bf16(ah[mi], bl[ni], acc[mi][ni], 0, 0, 0);
        acc[mi][ni] = __builtin_amdgcn_mfma_f32_16x16x32_bf16(al[mi], bh[ni], acc[mi][ni], 0, 0, 0);
      }
  }
  if (f32out) {
    float* C = (float*)Cout;
#pragma unroll
    for (int mi = 0; mi < 4; ++mi)
#pragma unroll
      for (int ni = 0; ni < 4; ++ni)
#pragma unroll
        for (int j = 0; j < 4; ++j) {
          int row = m0 + wm + mi * 16 + lg * 4 + j;
          int col = n0 + wn + ni * 16 + lm;
          C[(size_t)row * N + col] = acc[mi][ni][j];
        }
  } else {
    ushort* C = (ushort*)Cout;
#pragma unroll
    for (int mi = 0; mi < 4; ++mi)
#pragma unroll
      for (int ni = 0; ni < 4; ++ni)
#pragma unroll
        for (int j = 0; j < 4; ++j) {
          int row = m0 + wm + mi * 16 + lg * 4 + j;
          int col = n0 + wn + ni * 16 + lm;
          C[(size_t)row * N + col] = f2bf(acc[mi][ni][j]);
        }
  }
}

// ---------------- RoPE in-place on Q (scaled 1/sqrt(HD)) and K ----------------
__global__ __launch_bounds__(256) void rope2_kernel(ushort* __restrict__ Q,
                                                    ushort* __restrict__ K,
                                                    const int* __restrict__ pos,
                                                    const float* __restrict__ cosT,
                                                    const float* __restrict__ sinT) {
  int idx = blockIdx.x * 256 + threadIdx.x;  // S*1024 (pairs)
  int s = idx >> 10, dh = idx & 1023;
  int hh = dh >> 6, j = dh & 63;
  int p = pos[s];
  float cs = cosT[p * 64 + j], sn = sinT[p * 64 + j];
  size_t i1 = (size_t)s * DMODEL + hh * HEADDIM + j, i2 = i1 + 64;
  float q1 = bf2f(Q[i1]), q2 = bf2f(Q[i2]);
  float k1 = bf2f(K[i1]), k2 = bf2f(K[i2]);
  const float scl = 0.08838834764831845f;  // 1/sqrt(128)
  Q[i1] = f2bf((q1 * cs - q2 * sn) * scl);
  Q[i2] = f2bf((q2 * cs + q1 * sn) * scl);
  K[i1] = f2bf(k1 * cs - k2 * sn);
  K[i2] = f2bf(k2 * cs + k1 * sn);
}

// ---------------- V transpose: Vr [S][D] -> Vt [D][S] (bf16) ----------------
__global__ __launch_bounds__(256) void transpose_kernel(const ushort* __restrict__ Vr,
                                                        ushort* __restrict__ Vt) {
  __shared__ __align__(16) ushort tile[64 * 72];
  int tid = threadIdx.x;
  int s0 = blockIdx.x * 64, c0 = blockIdx.y * 64;
#pragma unroll
  for (int it = 0; it < 2; ++it) {
    int i = tid + it * 256;
    int r = i >> 3, c = i & 7;
    *reinterpret_cast<uint4*>(&tile[r * 72 + c * 8]) =
        *reinterpret_cast<const uint4*>(&Vr[(size_t)(s0 + r) * DMODEL + c0 + c * 8]);
  }
  __syncthreads();
#pragma unroll
  for (int it = 0; it < 2; ++it) {
    int i = tid + it * 256;
    int cr = i >> 3, sc = i & 7;
    ushort tmp[8];
#pragma unroll
    for (int j = 0; j < 8; ++j) tmp[j] = tile[(sc * 8 + j) * 72 + cr];
    *reinterpret_cast<uint4*>(&Vt[(size_t)(c0 + cr) * S_LEN + s0 + sc * 8]) =
        *reinterpret_cast<uint4*>(tmp);
  }
}

// ---------------- Flash attention v2: 8 waves, QBLK=128, KBLK=64 ----------------
#define KLD 136  // 128 + 8 pad (ushorts)
#define VLD 72   // 64 + 8
#define PLD 72

__global__ __launch_bounds__(512, 4) void flash2_kernel(const ushort* __restrict__ Q,
                                                        const ushort* __restrict__ Kb,
                                                        const ushort* __restrict__ Vt,
                                                        ushort* __restrict__ Oh,
                                                        ushort* __restrict__ Ol) {
  __shared__ __align__(16) ushort Kt[64 * KLD];
  __shared__ __align__(16) ushort Vs[HEADDIM * VLD];
  __shared__ __align__(16) ushort Ps[8][16 * PLD];
  const int tid = threadIdx.x;
  const int wave = tid >> 6, lane = tid & 63;
  const int lg = lane >> 4, lm = lane & 15;
  // XCD swizzle: dispatch id d -> original o; each XCD gets 64 consecutive o = 2 heads
  const int id = blockIdx.y * gridDim.x + blockIdx.x;  // 0..511
  const int o = (id & 7) * 64 + (id >> 3);
  const int h = o >> 5;
  const int q0 = (o & 31) * 128;
  const int qrow = q0 + wave * 16 + lm;

  bf16x8 qh[4];
#pragma unroll
  for (int kc = 0; kc < 4; ++kc)
    qh[kc] = *reinterpret_cast<const bf16x8*>(&Q[(size_t)qrow * DMODEL + h * HEADDIM + kc * 32 + lg * 8]);

  bf16x8 ones;
#pragma unroll
  for (int i = 0; i < 8; ++i) ones[i] = (short)0x3f80;  // bf16 1.0

  f32x4 oacc[8] = {};
  f32x4 osum = {};
  float mrun[4];
#pragma unroll
  for (int j = 0; j < 4; ++j) mrun[j] = -3.0e38f;

  for (int k0 = 0; k0 < S_LEN; k0 += 64) {
    __syncthreads();
#pragma unroll
    for (int it = 0; it < 2; ++it) {
      int i = tid + it * 512;
      int r = i >> 4, c = i & 15;  // K: 64 rows x 16 chunks
      *reinterpret_cast<uint4*>(&Kt[r * KLD + c * 8]) =
          *reinterpret_cast<const uint4*>(&Kb[(size_t)(k0 + r) * DMODEL + h * HEADDIM + c * 8]);
      int d = i >> 3, c2 = i & 7;  // V: 128 rows x 8 chunks
      *reinterpret_cast<uint4*>(&Vs[d * VLD + c2 * 8]) =
          *reinterpret_cast<const uint4*>(&Vt[(size_t)(h * HEADDIM + d) * S_LEN + k0 + c2 * 8]);
    }
    __syncthreads();

    // QK^T: 16 q-rows x 64 keys
    f32x4 sc4[4] = {};
#pragma unroll
    for (int nf = 0; nf < 4; ++nf)
#pragma unroll
      for (int kc = 0; kc < 4; ++kc) {
        bf16x8 kfrag = *reinterpret_cast<const bf16x8*>(&Kt[(nf * 16 + lm) * KLD + kc * 32 + lg * 8]);
        sc4[nf] = __builtin_amdgcn_mfma_f32_16x16x32_bf16(qh[kc], kfrag, sc4[nf], 0, 0, 0);
      }

    // row max (16-lane reduce)
    float mt[4];
#pragma unroll
    for (int j = 0; j < 4; ++j)
      mt[j] = fmaxf(fmaxf(sc4[0][j], sc4[1][j]), fmaxf(sc4[2][j], sc4[3][j]));
#pragma unroll
    for (int off = 1; off < 16; off <<= 1)
#pragma unroll
      for (int j = 0; j < 4; ++j) mt[j] = fmaxf(mt[j], __shfl_xor(mt[j], off));

    // defer-max: rescale only when max grew past threshold
    bool grow = false;
#pragma unroll
    for (int j = 0; j < 4; ++j) grow = grow || (mt[j] > mrun[j] + 8.0f);
    if (__any(grow)) {
#pragma unroll
      for (int j = 0; j < 4; ++j) {
        float mn = fmaxf(mrun[j], mt[j]);
        float scl = __expf(mrun[j] - mn);
        mrun[j] = mn;
        osum[j] *= scl;
#pragma unroll
        for (int nb = 0; nb < 8; ++nb) oacc[nb][j] *= scl;
      }
    }

    // P = exp(S - m), write to LDS for A-frag re-layout
#pragma unroll
    for (int nf = 0; nf < 4; ++nf)
#pragma unroll
      for (int j = 0; j < 4; ++j) {
        float p = __expf(sc4[nf][j] - mrun[j]);
        Ps[wave][(lg * 4 + j) * PLD + nf * 16 + lm] = f2bf(p);
      }
    bf16x8 pa[2];
#pragma unroll
    for (int kk = 0; kk < 2; ++kk)
      pa[kk] = *reinterpret_cast<const bf16x8*>(&Ps[wave][lm * PLD + kk * 32 + lg * 8]);

    // PV + row-sum via ones-MFMA
#pragma unroll
    for (int kk = 0; kk < 2; ++kk) {
      osum = __builtin_amdgcn_mfma_f32_16x16x32_bf16(pa[kk], ones, osum, 0, 0, 0);
#pragma unroll
      for (int nb = 0; nb < 8; ++nb) {
        bf16x8 vfrag = *reinterpret_cast<const bf16x8*>(&Vs[(nb * 16 + lm) * VLD + kk * 32 + lg * 8]);
        oacc[nb] = __builtin_amdgcn_mfma_f32_16x16x32_bf16(pa[kk], vfrag, oacc[nb], 0, 0, 0);
      }
    }
  }

  float linv[4];
#pragma unroll
  for (int j = 0; j < 4; ++j) linv[j] = 1.0f / osum[j];
#pragma unroll
  for (int nb = 0; nb < 8; ++nb)
#pragma unroll
    for (int j = 0; j < 4; ++j) {
      int row = q0 + wave * 16 + lg * 4 + j;
      int col = h * HEADDIM + nb * 16 + lm;
      float ov = oacc[nb][j] * linv[j];
      ushort hi, lo;
      splitf(ov, hi, lo);
      Oh[(size_t)row * DMODEL + col] = hi;
      Ol[(size_t)row * DMODEL + col] = lo;
    }
}

extern "C" void kernel_launch(void* const* d_in, const int* in_sizes, int n_in,
                              void* d_out, int out_size, void* d_ws, size_t ws_size,
                              hipStream_t stream) {
  (void)in_sizes; (void)n_in; (void)out_size; (void)ws_size;
  const float* X  = (const float*)d_in[0];
  const float* Wq = (const float*)d_in[1];
  const float* Wk = (const float*)d_in[2];
  const float* Wv = (const float*)d_in[3];
  const float* Wo = (const float*)d_in[4];
  const int* pos  = (const int*)d_in[5];
  float* out = (float*)d_out;

  ushort* wb = (ushort*)d_ws;
  const size_t SD = (size_t)S_LEN * DMODEL;       // 8388608 elements
  const size_t DD = (size_t)DMODEL * DMODEL;      // 4194304 elements (one weight matrix)

  ushort* Xh = wb;             // slot0: later Ol
  ushort* Xl = wb + SD;        // slot1
  ushort* Qr = wb + 2 * SD;    // slot2: roped in place
  ushort* Kr = wb + 3 * SD;    // slot3
  ushort* Vr = wb + 4 * SD;    // slot4: later Oh
  ushort* Vt = wb + 5 * SD;    // slot5
  ushort* W0h = wb + 6 * SD;           // Wq, then Wo (hi: DD elems, lo: DD elems = 1 slot)
  ushort* W0l = wb + 6 * SD + DD;
  ushort* W1h = wb + 7 * SD;           // Wk
  ushort* W1l = wb + 7 * SD + DD;
  ushort* W2h = wb + 8 * SD;           // Wv
  ushort* W2l = wb + 8 * SD + DD;
  float* cosT = (float*)(wb + 9 * SD);
  float* sinT = cosT + (size_t)S_LEN * 64;
  ushort* OhB = Vr;  // reuse
  ushort* OlB = Xh;  // reuse
  // total: 9*SD*2 + 2*S*64*4 bytes = 153.1 MB

  rope_table_kernel<<<S_LEN * 64 / 256, 256, 0, stream>>>(cosT, sinT);
  split_kernel<<<SD / 1024, 256, 0, stream>>>(X, Xh, Xl);
  split_kernel<<<DD / 1024, 256, 0, stream>>>(Wq, W0h, W0l);
  split_kernel<<<DD / 1024, 256, 0, stream>>>(Wk, W1h, W1l);
  split_kernel<<<DD / 1024, 256, 0, stream>>>(Wv, W2h, W2l);

  dim3 gemmGrid(DMODEL / 128, S_LEN / 128);
  gemm3<<<gemmGrid, 256, 0, stream>>>(Xh, Xl, W0h, W0l, Qr, S_LEN, DMODEL, DMODEL, 0);
  split_kernel<<<DD / 1024, 256, 0, stream>>>(Wo, W0h, W0l);  // after Q-GEMM
  gemm3<<<gemmGrid, 256, 0, stream>>>(Xh, Xl, W1h, W1l, Kr, S_LEN, DMODEL, DMODEL, 0);
  gemm3<<<gemmGrid, 256, 0, stream>>>(Xh, Xl, W2h, W2l, Vr, S_LEN, DMODEL, DMODEL, 0);

  rope2_kernel<<<(S_LEN * 1024) / 256, 256, 0, stream>>>(Qr, Kr, pos, cosT, sinT);
  transpose_kernel<<<dim3(S_LEN / 64, DMODEL / 64), 256, 0, stream>>>(Vr, Vt);

  flash2_kernel<<<dim3(S_LEN / 128, NHEADS), 512, 0, stream>>>(Qr, Kr, Vt, OhB, OlB);

  gemm3<<<gemmGrid, 256, 0, stream>>>(OhB, OlB, W0h, W0l, out, S_LEN, DMODEL, DMODEL, 1);
}